// Round 5
// baseline (172.934 us; speedup 1.0000x reference)
//
#include <hip/hip_runtime.h>
#include <math.h>

#define HIDDEN 128
#define SCALE 0.25f

typedef __attribute__((ext_vector_type(8))) short short8v;
typedef __attribute__((ext_vector_type(4))) float f32x4;

__device__ __forceinline__ unsigned short f2bf(float f) {
  const unsigned u = __float_as_uint(f);
  const unsigned r = u + 0x7fffu + ((u >> 16) & 1u);   // RNE
  return (unsigned short)(r >> 16);
}
__device__ __forceinline__ float bflo(unsigned u) { return __uint_as_float(u << 16); }
__device__ __forceinline__ float bfhi(unsigned u) { return __uint_as_float(u & 0xffff0000u); }

// blocks 0..31: build fragment-ordered bf16 weights (chunk l -> W[n*16+(l&15)][kk*32+(l>>4)*8+0..7])
// blocks 32.. : count edges per destination.
__global__ __launch_bounds__(256) void prep_kernel(
    const float* __restrict__ W0, const float* __restrict__ W1,
    const float* __restrict__ W2, const float* __restrict__ W3,
    unsigned short* __restrict__ Wfrag,
    const int* __restrict__ ei, int E, int* __restrict__ counts)
{
  if (blockIdx.x < 32) {
    const int chunk = blockIdx.x * 256 + threadIdx.x;   // 8192 chunks
    const int m = chunk >> 11;
    const int rem = chunk & 2047;
    const int l = rem & 63;
    const int nkk = rem >> 6;
    const int n = nkk >> 2, kk = nkk & 3;
    const float* W = (m == 0) ? W0 : (m == 1) ? W1 : (m == 2) ? W2 : W3;
    const int row = n * 16 + (l & 15);
    const int k0 = kk * 32 + (l >> 4) * 8;
    const float4 v0 = *(const float4*)&W[row * 128 + k0];
    const float4 v1 = *(const float4*)&W[row * 128 + k0 + 4];
    uint4 o;
    o.x = (unsigned)f2bf(v0.x) | ((unsigned)f2bf(v0.y) << 16);
    o.y = (unsigned)f2bf(v0.z) | ((unsigned)f2bf(v0.w) << 16);
    o.z = (unsigned)f2bf(v1.x) | ((unsigned)f2bf(v1.y) << 16);
    o.w = (unsigned)f2bf(v1.z) | ((unsigned)f2bf(v1.w) << 16);
    *(uint4*)&Wfrag[(size_t)chunk * 8] = o;
  } else {
    const int e = ((blockIdx.x - 32) * 256 + threadIdx.x) * 4;
    if (e + 4 <= E) {
      const int4 d = *(const int4*)&ei[E + e];
      atomicAdd(&counts[d.x], 1);
      atomicAdd(&counts[d.y], 1);
      atomicAdd(&counts[d.z], 1);
      atomicAdd(&counts[d.w], 1);
    } else {
      for (int k = e; k < E; ++k) atomicAdd(&counts[ei[E + k]], 1);
    }
  }
}

// Stage 64 X rows (f32->bf16) into XOR-swizzled LDS; returns nothing (helper inlined).
// Fused Q/K/V projection. Blocks [0,gb_src): K+V on x_src (shared X tile, dual
// accumulators); blocks [gb_src,..): Q on x_dst. B-fragments straight from global
// (L2-hot). C/D: row=(l>>4)*4+r, col=l&15.
__global__ __launch_bounds__(256) void qkv_gemm_kernel(
    const float* __restrict__ x_src, const float* __restrict__ x_dst,
    const unsigned short* __restrict__ Wfrag,   // [Wq|Wk|Wv|Wo] * 16384
    const float* __restrict__ bq, const float* __restrict__ bk,
    const float* __restrict__ bv,
    unsigned short* __restrict__ qb, unsigned short* __restrict__ kvb,
    int Nsrc, int Ndst, int gb_src)
{
  __shared__ __align__(16) char XsB[64 * 256];
  const int t = threadIdx.x;
  const bool isQ = (int)blockIdx.x >= gb_src;
  const int blk = isQ ? ((int)blockIdx.x - gb_src) : (int)blockIdx.x;
  const int N = isQ ? Ndst : Nsrc;
  const float* Xf = isQ ? x_dst : x_src;
  const int row_base = blk * 64;

  float4 xv[8];
  #pragma unroll
  for (int it = 0; it < 8; ++it) {
    const int c = t + it * 256;
    const int row = c >> 5, fc = (c & 31) << 2;
    const int g = row_base + row;
    xv[it] = make_float4(0.f, 0.f, 0.f, 0.f);
    if (g < N) xv[it] = *(const float4*)&Xf[(size_t)g * 128 + fc];
  }
  #pragma unroll
  for (int it = 0; it < 8; ++it) {
    const int c = t + it * 256;
    const int row = c >> 5, b8 = (c & 31) << 3;
    uint2 p;
    p.x = (unsigned)f2bf(xv[it].x) | ((unsigned)f2bf(xv[it].y) << 16);
    p.y = (unsigned)f2bf(xv[it].z) | ((unsigned)f2bf(xv[it].w) << 16);
    *(uint2*)&XsB[row * 256 + (b8 ^ ((row & 7) << 4))] = p;
  }
  __syncthreads();

  const int l = t & 63, w = t >> 6;
  const int r16 = l & 15, g16 = l >> 4;
  const int sw = (r16 & 7) << 4;
  const char* ax = &XsB[(w * 16 + r16) * 256];

  if (isQ) {
    f32x4 acc[8];
    #pragma unroll
    for (int n = 0; n < 8; ++n) acc[n] = (f32x4){0.f, 0.f, 0.f, 0.f};
    const short8v* wf = (const short8v*)Wfrag + l;          // Wq
    #pragma unroll
    for (int kk = 0; kk < 4; ++kk) {
      const short8v a = *(const short8v*)(ax + ((kk * 64 + g16 * 16) ^ sw));
      #pragma unroll
      for (int n = 0; n < 8; ++n)
        acc[n] = __builtin_amdgcn_mfma_f32_16x16x32_bf16(a, wf[(n * 4 + kk) * 64], acc[n], 0, 0, 0);
    }
    #pragma unroll
    for (int n = 0; n < 8; ++n) {
      const int col = n * 16 + r16;
      const float bvv = bq[col];
      #pragma unroll
      for (int r = 0; r < 4; ++r) {
        const int g = row_base + w * 16 + g16 * 4 + r;
        if (g < N) qb[(size_t)g * 128 + col] = f2bf(acc[n][r] + bvv);
      }
    }
  } else {
    f32x4 accK[8], accV[8];
    #pragma unroll
    for (int n = 0; n < 8; ++n) {
      accK[n] = (f32x4){0.f, 0.f, 0.f, 0.f};
      accV[n] = (f32x4){0.f, 0.f, 0.f, 0.f};
    }
    const short8v* wfk = (const short8v*)(Wfrag + 16384) + l;  // Wk
    const short8v* wfv = (const short8v*)(Wfrag + 32768) + l;  // Wv
    #pragma unroll
    for (int kk = 0; kk < 4; ++kk) {
      const short8v a = *(const short8v*)(ax + ((kk * 64 + g16 * 16) ^ sw));
      #pragma unroll
      for (int n = 0; n < 8; ++n) {
        accK[n] = __builtin_amdgcn_mfma_f32_16x16x32_bf16(a, wfk[(n * 4 + kk) * 64], accK[n], 0, 0, 0);
        accV[n] = __builtin_amdgcn_mfma_f32_16x16x32_bf16(a, wfv[(n * 4 + kk) * 64], accV[n], 0, 0, 0);
      }
    }
    #pragma unroll
    for (int n = 0; n < 8; ++n) {
      const int col = n * 16 + r16;
      const float bkk = bk[col], bvv = bv[col];
      #pragma unroll
      for (int r = 0; r < 4; ++r) {
        const int g = row_base + w * 16 + g16 * 4 + r;
        if (g < N) {
          kvb[(size_t)g * 256 + col]       = f2bf(accK[n][r] + bkk);
          kvb[(size_t)g * 256 + 128 + col] = f2bf(accV[n][r] + bvv);
        }
      }
    }
  }
}

// Output projection: aggb (bf16, stride 128) x Wo -> f32 out.
__global__ __launch_bounds__(256) void out_gemm_kernel(
    const unsigned short* __restrict__ Xh,
    const unsigned short* __restrict__ Wfrag_o,
    const float* __restrict__ bo, float* __restrict__ Y, int N)
{
  __shared__ __align__(16) char XsB[64 * 256];
  const int t = threadIdx.x;
  const int row_base = blockIdx.x * 64;

  uint2 hv[8];
  #pragma unroll
  for (int it = 0; it < 8; ++it) {
    const int c = t + it * 256;
    const int row = c >> 5, fc = (c & 31) << 2;
    const int g = row_base + row;
    hv[it] = make_uint2(0, 0);
    if (g < N) hv[it] = *(const uint2*)&Xh[(size_t)g * 128 + fc];
  }
  #pragma unroll
  for (int it = 0; it < 8; ++it) {
    const int c = t + it * 256;
    const int row = c >> 5, b8 = (c & 31) << 3;
    *(uint2*)&XsB[row * 256 + (b8 ^ ((row & 7) << 4))] = hv[it];
  }
  __syncthreads();

  const int l = t & 63, w = t >> 6;
  const int r16 = l & 15, g16 = l >> 4;
  const int sw = (r16 & 7) << 4;
  f32x4 acc[8];
  #pragma unroll
  for (int n = 0; n < 8; ++n) acc[n] = (f32x4){0.f, 0.f, 0.f, 0.f};
  const char* ax = &XsB[(w * 16 + r16) * 256];
  const short8v* wf = (const short8v*)Wfrag_o + l;
  #pragma unroll
  for (int kk = 0; kk < 4; ++kk) {
    const short8v a = *(const short8v*)(ax + ((kk * 64 + g16 * 16) ^ sw));
    #pragma unroll
    for (int n = 0; n < 8; ++n)
      acc[n] = __builtin_amdgcn_mfma_f32_16x16x32_bf16(a, wf[(n * 4 + kk) * 64], acc[n], 0, 0, 0);
  }
  #pragma unroll
  for (int n = 0; n < 8; ++n) {
    const int col = n * 16 + r16;
    const float bvv = bo[col];
    #pragma unroll
    for (int r = 0; r < 4; ++r) {
      const int g = row_base + w * 16 + g16 * 4 + r;
      if (g < N) Y[(size_t)g * 128 + col] = acc[n][r] + bvv;
    }
  }
}

__global__ __launch_bounds__(256) void reduce_counts_kernel(
    const int* __restrict__ counts, int n, int* __restrict__ bsums)
{
  const int idx = blockIdx.x * 256 + threadIdx.x;
  int x = (idx < n) ? counts[idx] : 0;
  #pragma unroll
  for (int off = 1; off < 64; off <<= 1) x += __shfl_xor(x, off);
  __shared__ int ws[4];
  if ((threadIdx.x & 63) == 0) ws[threadIdx.x >> 6] = x;
  __syncthreads();
  if (threadIdx.x == 0) bsums[blockIdx.x] = ws[0] + ws[1] + ws[2] + ws[3];
}

__global__ __launch_bounds__(256) void scan_bsums_kernel(int* bsums, int nb)
{
  __shared__ int buf[256];
  const int t = threadIdx.x;
  const int x = (t < nb) ? bsums[t] : 0;
  buf[t] = x;
  __syncthreads();
  int val = x;
  #pragma unroll
  for (int off = 1; off < 256; off <<= 1) {
    const int other = (t >= off) ? buf[t - off] : 0;
    __syncthreads();
    val += other;
    buf[t] = val;
    __syncthreads();
  }
  if (t < nb) bsums[t] = val - x;
}

__global__ __launch_bounds__(256) void scan_counts_kernel(
    const int* __restrict__ counts, int n, const int* __restrict__ bsums,
    int* __restrict__ offsets)
{
  const int idx = blockIdx.x * 256 + threadIdx.x;
  const int lane = threadIdx.x & 63, wid = threadIdx.x >> 6;
  const int x = (idx < n) ? counts[idx] : 0;
  int v = x;
  #pragma unroll
  for (int off = 1; off < 64; off <<= 1) {
    const int t2 = __shfl_up(v, off);
    if (lane >= off) v += t2;
  }
  __shared__ int wsum[4];
  if (lane == 63) wsum[wid] = v;
  __syncthreads();
  int wbase = 0;
  for (int p = 0; p < wid; ++p) wbase += wsum[p];
  if (idx < n) offsets[idx] = bsums[blockIdx.x] + wbase + v - x;
}

__global__ __launch_bounds__(256) void scatter_kernel(
    const int* __restrict__ ei, int E, const int* __restrict__ offsets,
    int* __restrict__ cursor, int* __restrict__ csr_src)
{
  const int e = (blockIdx.x * 256 + threadIdx.x) * 4;
  if (e + 4 <= E) {
    const int4 s = *(const int4*)&ei[e];
    const int4 d = *(const int4*)&ei[E + e];
    int p;
    p = atomicAdd(&cursor[d.x], 1); csr_src[offsets[d.x] + p] = s.x;
    p = atomicAdd(&cursor[d.y], 1); csr_src[offsets[d.y] + p] = s.y;
    p = atomicAdd(&cursor[d.z], 1); csr_src[offsets[d.z] + p] = s.z;
    p = atomicAdd(&cursor[d.w], 1); csr_src[offsets[d.w] + p] = s.w;
  } else {
    for (int k = e; k < E; ++k) {
      const int d = ei[E + k];
      const int p = atomicAdd(&cursor[d], 1);
      csr_src[offsets[d] + p] = ei[k];
    }
  }
}

// One wave per destination; lane = (edge-slot eg=lane>>3, head h=lane&7).
// Each lane computes the FULL 16-dim dot for its (edge,head): no shfl in loop,
// 8 edges per iteration, exp once per (edge,head). Per-dst 3-step reduction at end.
// kvb row: [k 128 bf16 | v 128 bf16]; head h occupies dims h*16..h*16+15.
__global__ __launch_bounds__(256) void edge_attn_kernel(
    const unsigned short* __restrict__ qb, const unsigned short* __restrict__ kvb,
    const float* __restrict__ eb, const int* __restrict__ offsets,
    const int* __restrict__ counts, const int* __restrict__ csr_src,
    unsigned short* __restrict__ agg, int Ndst)
{
  const int wave = blockIdx.x * 4 + (threadIdx.x >> 6);
  if (wave >= Ndst) return;
  const int lane = threadIdx.x & 63;
  const int eg = lane >> 3, h = lane & 7;

  const uint4 q0 = *(const uint4*)&qb[(size_t)wave * 128 + h * 16];
  const uint4 q1 = *(const uint4*)&qb[(size_t)wave * 128 + h * 16 + 8];
  const float bias = eb[h];
  const int ro = offsets[wave];
  const int cnt = counts[wave];

  float acc[16];
  #pragma unroll
  for (int j = 0; j < 16; ++j) acc[j] = 0.f;
  float s = 0.f;

  for (int it = 0; it * 8 < cnt; ++it) {
    const int e = it * 8 + eg;
    const bool act = e < cnt;
    const int src = act ? csr_src[ro + e] : 0;
    const size_t base = (size_t)src * 256 + h * 16;
    const uint4 k0 = *(const uint4*)&kvb[base];
    const uint4 k1 = *(const uint4*)&kvb[base + 8];
    const uint4 v0 = *(const uint4*)&kvb[base + 128];
    const uint4 v1 = *(const uint4*)&kvb[base + 136];

    float p = 0.f;
    p = fmaf(bflo(q0.x), bflo(k0.x), p); p = fmaf(bfhi(q0.x), bfhi(k0.x), p);
    p = fmaf(bflo(q0.y), bflo(k0.y), p); p = fmaf(bfhi(q0.y), bfhi(k0.y), p);
    p = fmaf(bflo(q0.z), bflo(k0.z), p); p = fmaf(bfhi(q0.z), bfhi(k0.z), p);
    p = fmaf(bflo(q0.w), bflo(k0.w), p); p = fmaf(bfhi(q0.w), bfhi(k0.w), p);
    p = fmaf(bflo(q1.x), bflo(k1.x), p); p = fmaf(bfhi(q1.x), bfhi(k1.x), p);
    p = fmaf(bflo(q1.y), bflo(k1.y), p); p = fmaf(bfhi(q1.y), bfhi(k1.y), p);
    p = fmaf(bflo(q1.z), bflo(k1.z), p); p = fmaf(bfhi(q1.z), bfhi(k1.z), p);
    p = fmaf(bflo(q1.w), bflo(k1.w), p); p = fmaf(bfhi(q1.w), bfhi(k1.w), p);

    const float wgt = act ? __expf(fmaf(p, SCALE, bias)) : 0.f;
    s += wgt;
    acc[0]  = fmaf(wgt, bflo(v0.x), acc[0]);  acc[1]  = fmaf(wgt, bfhi(v0.x), acc[1]);
    acc[2]  = fmaf(wgt, bflo(v0.y), acc[2]);  acc[3]  = fmaf(wgt, bfhi(v0.y), acc[3]);
    acc[4]  = fmaf(wgt, bflo(v0.z), acc[4]);  acc[5]  = fmaf(wgt, bfhi(v0.z), acc[5]);
    acc[6]  = fmaf(wgt, bflo(v0.w), acc[6]);  acc[7]  = fmaf(wgt, bfhi(v0.w), acc[7]);
    acc[8]  = fmaf(wgt, bflo(v1.x), acc[8]);  acc[9]  = fmaf(wgt, bfhi(v1.x), acc[9]);
    acc[10] = fmaf(wgt, bflo(v1.y), acc[10]); acc[11] = fmaf(wgt, bfhi(v1.y), acc[11]);
    acc[12] = fmaf(wgt, bflo(v1.z), acc[12]); acc[13] = fmaf(wgt, bfhi(v1.z), acc[13]);
    acc[14] = fmaf(wgt, bflo(v1.w), acc[14]); acc[15] = fmaf(wgt, bfhi(v1.w), acc[15]);
  }

  #pragma unroll
  for (int m = 8; m <= 32; m <<= 1) {
    s += __shfl_xor(s, m);
    #pragma unroll
    for (int j = 0; j < 16; ++j) acc[j] += __shfl_xor(acc[j], m);
  }

  if (eg == 0) {
    const float rs = 1.0f / (s + 1e-8f);
    uint4 o0, o1;
    o0.x = (unsigned)f2bf(acc[0] * rs)  | ((unsigned)f2bf(acc[1] * rs) << 16);
    o0.y = (unsigned)f2bf(acc[2] * rs)  | ((unsigned)f2bf(acc[3] * rs) << 16);
    o0.z = (unsigned)f2bf(acc[4] * rs)  | ((unsigned)f2bf(acc[5] * rs) << 16);
    o0.w = (unsigned)f2bf(acc[6] * rs)  | ((unsigned)f2bf(acc[7] * rs) << 16);
    o1.x = (unsigned)f2bf(acc[8] * rs)  | ((unsigned)f2bf(acc[9] * rs) << 16);
    o1.y = (unsigned)f2bf(acc[10] * rs) | ((unsigned)f2bf(acc[11] * rs) << 16);
    o1.z = (unsigned)f2bf(acc[12] * rs) | ((unsigned)f2bf(acc[13] * rs) << 16);
    o1.w = (unsigned)f2bf(acc[14] * rs) | ((unsigned)f2bf(acc[15] * rs) << 16);
    *(uint4*)&agg[(size_t)wave * 128 + h * 16] = o0;
    *(uint4*)&agg[(size_t)wave * 128 + h * 16 + 8] = o1;
  }
}

extern "C" void kernel_launch(void* const* d_in, const int* in_sizes, int n_in,
                              void* d_out, int out_size, void* d_ws, size_t ws_size,
                              hipStream_t stream) {
  const float* x_src = (const float*)d_in[0];
  const float* x_dst = (const float*)d_in[1];
  const int*   ei    = (const int*)d_in[2];
  const float* Wq = (const float*)d_in[3];
  const float* bq = (const float*)d_in[4];
  const float* Wk = (const float*)d_in[5];
  const float* bk = (const float*)d_in[6];
  const float* Wv = (const float*)d_in[7];
  const float* bv = (const float*)d_in[8];
  const float* Wo = (const float*)d_in[9];
  const float* bo = (const float*)d_in[10];
  const float* eb = (const float*)d_in[11];

  const int Nsrc = in_sizes[0] / HIDDEN;
  const int Ndst = in_sizes[1] / HIDDEN;
  const int E    = in_sizes[2] / 2;

  char* w = (char*)d_ws;
  unsigned short* qb   = (unsigned short*)w; w += (size_t)Ndst * 128 * 2;
  unsigned short* kvb  = (unsigned short*)w; w += (size_t)Nsrc * 256 * 2;
  unsigned short* aggb = (unsigned short*)w; w += (size_t)Ndst * 128 * 2;
  unsigned short* Wb   = (unsigned short*)w; w += (size_t)4 * 16384 * 2;
  int* counts  = (int*)w; w += (size_t)Ndst * sizeof(int);
  int* cursor  = (int*)w; w += (size_t)Ndst * sizeof(int);
  int* offsets = (int*)w; w += (size_t)Ndst * sizeof(int);
  int* bsums   = (int*)w; w += 256 * sizeof(int);
  int* csr_src = (int*)w; w += (size_t)E * sizeof(int);

  hipMemsetAsync(counts, 0, (size_t)Ndst * 2 * sizeof(int), stream);  // counts+cursor

  dim3 blk256(256);
  const int e4blocks = (E / 4 + 255) / 256;
  prep_kernel<<<32 + e4blocks, blk256, 0, stream>>>(Wq, Wk, Wv, Wo, Wb, ei, E, counts);

  const int gb_dst = (Ndst + 63) / 64;
  const int gb_src = (Nsrc + 63) / 64;
  qkv_gemm_kernel<<<gb_src + gb_dst, blk256, 0, stream>>>(
      x_src, x_dst, Wb, bq, bk, bv, qb, kvb, Nsrc, Ndst, gb_src);

  const int nb = (Ndst + 255) / 256;
  reduce_counts_kernel<<<nb, blk256, 0, stream>>>(counts, Ndst, bsums);
  scan_bsums_kernel<<<1, blk256, 0, stream>>>(bsums, nb);
  scan_counts_kernel<<<nb, blk256, 0, stream>>>(counts, Ndst, bsums, offsets);

  scatter_kernel<<<e4blocks, blk256, 0, stream>>>(ei, E, offsets, cursor, csr_src);

  const int ablocks = (Ndst + 3) / 4;
  edge_attn_kernel<<<ablocks, blk256, 0, stream>>>(qb, kvb, eb, offsets, counts,
                                                   csr_src, aggb, Ndst);

  out_gemm_kernel<<<gb_dst, blk256, 0, stream>>>(aggb, Wb + 49152, bo, (float*)d_out, Ndst);
}

// Round 6
// 152.980 us; speedup vs baseline: 1.1304x; 1.1304x over previous
//
#include <hip/hip_runtime.h>
#include <math.h>

#define HIDDEN 128
#define SCALE 0.25f

typedef __attribute__((ext_vector_type(8))) short short8v;
typedef __attribute__((ext_vector_type(4))) float f32x4;

__device__ __forceinline__ unsigned short f2bf(float f) {
  const unsigned u = __float_as_uint(f);
  const unsigned r = u + 0x7fffu + ((u >> 16) & 1u);   // RNE
  return (unsigned short)(r >> 16);
}
__device__ __forceinline__ float bflo(unsigned u) { return __uint_as_float(u << 16); }
__device__ __forceinline__ float bfhi(unsigned u) { return __uint_as_float(u & 0xffff0000u); }

__device__ __forceinline__ void gload_lds16(const void* g, void* l) {
  __builtin_amdgcn_global_load_lds(
      (const __attribute__((address_space(1))) unsigned*)g,
      (__attribute__((address_space(3))) unsigned*)l, 16, 0, 0);
}

// blocks 0..31: build fragment-ordered bf16 weights (chunk l -> W[n*16+(l&15)][kk*32+(l>>4)*8+0..7])
// blocks 32.. : count edges per destination.
__global__ __launch_bounds__(256) void prep_kernel(
    const float* __restrict__ W0, const float* __restrict__ W1,
    const float* __restrict__ W2, const float* __restrict__ W3,
    unsigned short* __restrict__ Wfrag,
    const int* __restrict__ ei, int E, int* __restrict__ counts)
{
  if (blockIdx.x < 32) {
    const int chunk = blockIdx.x * 256 + threadIdx.x;   // 8192 chunks
    const int m = chunk >> 11;
    const int rem = chunk & 2047;
    const int l = rem & 63;
    const int nkk = rem >> 6;
    const int n = nkk >> 2, kk = nkk & 3;
    const float* W = (m == 0) ? W0 : (m == 1) ? W1 : (m == 2) ? W2 : W3;
    const int row = n * 16 + (l & 15);
    const int k0 = kk * 32 + (l >> 4) * 8;
    const float4 v0 = *(const float4*)&W[row * 128 + k0];
    const float4 v1 = *(const float4*)&W[row * 128 + k0 + 4];
    uint4 o;
    o.x = (unsigned)f2bf(v0.x) | ((unsigned)f2bf(v0.y) << 16);
    o.y = (unsigned)f2bf(v0.z) | ((unsigned)f2bf(v0.w) << 16);
    o.z = (unsigned)f2bf(v1.x) | ((unsigned)f2bf(v1.y) << 16);
    o.w = (unsigned)f2bf(v1.z) | ((unsigned)f2bf(v1.w) << 16);
    *(uint4*)&Wfrag[(size_t)chunk * 8] = o;
  } else {
    const int e = ((blockIdx.x - 32) * 256 + threadIdx.x) * 4;
    if (e + 4 <= E) {
      const int4 d = *(const int4*)&ei[E + e];
      atomicAdd(&counts[d.x], 1);
      atomicAdd(&counts[d.y], 1);
      atomicAdd(&counts[d.z], 1);
      atomicAdd(&counts[d.w], 1);
    } else {
      for (int k = e; k < E; ++k) atomicAdd(&counts[ei[E + k]], 1);
    }
  }
}

// Fused Q/K/V projection. Blocks [0,gb_src): K+V on x_src; [gb_src,..): Q on x_dst.
// W-fragments staged to LDS via global_load_lds (linear copy, fragment order ->
// conflict-free ds_read_b128 B reads). X: f32 loads -> bf16 -> XOR-swizzled LDS.
__global__ __launch_bounds__(256) void qkv_gemm_kernel(
    const float* __restrict__ x_src, const float* __restrict__ x_dst,
    const unsigned short* __restrict__ Wfrag,   // [Wq|Wk|Wv|Wo] * 16384
    const float* __restrict__ bq, const float* __restrict__ bk,
    const float* __restrict__ bv,
    unsigned short* __restrict__ qb, unsigned short* __restrict__ kvb,
    int Nsrc, int Ndst, int gb_src)
{
  __shared__ __align__(16) char XsB[64 * 256];   // 16KB
  __shared__ __align__(16) char WsB[65536];      // 64KB: [Wk|Wv] or [Wq]
  const int t = threadIdx.x;
  const bool isQ = (int)blockIdx.x >= gb_src;
  const int blk = isQ ? ((int)blockIdx.x - gb_src) : (int)blockIdx.x;
  const int N = isQ ? Ndst : Nsrc;
  const float* Xf = isQ ? x_dst : x_src;
  const int row_base = blk * 64;

  // Stage W: linear async copy (dest = uniform + lane*16 -- required pattern).
  const char* wsrc = (const char*)(Wfrag + (isQ ? 0 : 16384));
  if (isQ) {
    #pragma unroll
    for (int it = 0; it < 8; ++it) {
      const int off = (it * 256 + t) * 16;
      gload_lds16(wsrc + off, WsB + off);
    }
  } else {
    #pragma unroll
    for (int it = 0; it < 16; ++it) {
      const int off = (it * 256 + t) * 16;
      gload_lds16(wsrc + off, WsB + off);
    }
  }

  // Stage X: batched f32 loads, convert, swizzled LDS writes.
  float4 xv[8];
  #pragma unroll
  for (int it = 0; it < 8; ++it) {
    const int c = t + it * 256;
    const int row = c >> 5, fc = (c & 31) << 2;
    const int g = row_base + row;
    xv[it] = make_float4(0.f, 0.f, 0.f, 0.f);
    if (g < N) xv[it] = *(const float4*)&Xf[(size_t)g * 128 + fc];
  }
  #pragma unroll
  for (int it = 0; it < 8; ++it) {
    const int c = t + it * 256;
    const int row = c >> 5, b8 = (c & 31) << 3;
    uint2 p;
    p.x = (unsigned)f2bf(xv[it].x) | ((unsigned)f2bf(xv[it].y) << 16);
    p.y = (unsigned)f2bf(xv[it].z) | ((unsigned)f2bf(xv[it].w) << 16);
    *(uint2*)&XsB[row * 256 + (b8 ^ ((row & 7) << 4))] = p;
  }
  __syncthreads();

  const int l = t & 63, w = t >> 6;
  const int r16 = l & 15, g16 = l >> 4;
  const int sw = (r16 & 7) << 4;
  const char* ax = &XsB[(w * 16 + r16) * 256];

  if (isQ) {
    f32x4 acc[8];
    #pragma unroll
    for (int n = 0; n < 8; ++n) acc[n] = (f32x4){0.f, 0.f, 0.f, 0.f};
    #pragma unroll
    for (int kk = 0; kk < 4; ++kk) {
      const short8v a = *(const short8v*)(ax + ((kk * 64 + g16 * 16) ^ sw));
      #pragma unroll
      for (int n = 0; n < 8; ++n) {
        const short8v b = *(const short8v*)&WsB[((n * 4 + kk) * 64 + l) * 16];
        acc[n] = __builtin_amdgcn_mfma_f32_16x16x32_bf16(a, b, acc[n], 0, 0, 0);
      }
    }
    #pragma unroll
    for (int n = 0; n < 8; ++n) {
      const int col = n * 16 + r16;
      const float bvv = bq[col];
      #pragma unroll
      for (int r = 0; r < 4; ++r) {
        const int g = row_base + w * 16 + g16 * 4 + r;
        if (g < N) qb[(size_t)g * 128 + col] = f2bf(acc[n][r] + bvv);
      }
    }
  } else {
    f32x4 accK[8], accV[8];
    #pragma unroll
    for (int n = 0; n < 8; ++n) {
      accK[n] = (f32x4){0.f, 0.f, 0.f, 0.f};
      accV[n] = (f32x4){0.f, 0.f, 0.f, 0.f};
    }
    #pragma unroll
    for (int kk = 0; kk < 4; ++kk) {
      const short8v a = *(const short8v*)(ax + ((kk * 64 + g16 * 16) ^ sw));
      #pragma unroll
      for (int n = 0; n < 8; ++n) {
        const short8v bKv = *(const short8v*)&WsB[((n * 4 + kk) * 64 + l) * 16];
        const short8v bVv = *(const short8v*)&WsB[32768 + ((n * 4 + kk) * 64 + l) * 16];
        accK[n] = __builtin_amdgcn_mfma_f32_16x16x32_bf16(a, bKv, accK[n], 0, 0, 0);
        accV[n] = __builtin_amdgcn_mfma_f32_16x16x32_bf16(a, bVv, accV[n], 0, 0, 0);
      }
    }
    #pragma unroll
    for (int n = 0; n < 8; ++n) {
      const int col = n * 16 + r16;
      const float bkk = bk[col], bvv = bv[col];
      #pragma unroll
      for (int r = 0; r < 4; ++r) {
        const int g = row_base + w * 16 + g16 * 4 + r;
        if (g < N) {
          kvb[(size_t)g * 256 + col]       = f2bf(accK[n][r] + bkk);
          kvb[(size_t)g * 256 + 128 + col] = f2bf(accV[n][r] + bvv);
        }
      }
    }
  }
}

// Output projection: aggb (bf16) x Wo -> f32 out. Both operands staged via
// global_load_lds; X uses pre-swizzled SOURCE addresses (linear LDS dest).
__global__ __launch_bounds__(256) void out_gemm_kernel(
    const unsigned short* __restrict__ Xh,
    const unsigned short* __restrict__ Wfrag_o,
    const float* __restrict__ bo, float* __restrict__ Y, int N)
{
  __shared__ __align__(16) char XsB[64 * 256];   // 16KB
  __shared__ __align__(16) char WsB[32768];      // 32KB
  const int t = threadIdx.x;
  const int row_base = blockIdx.x * 64;

  #pragma unroll
  for (int it = 0; it < 8; ++it) {
    const int off = (it * 256 + t) * 16;
    gload_lds16((const char*)Wfrag_o + off, WsB + off);
  }
  // X: linear dest + inverse-swizzled source (swizzle is chunk-granular:
  // src chunk = c16 ^ (row&7); reads past N land in allocated ws (unused rows).
  #pragma unroll
  for (int it = 0; it < 4; ++it) {
    const int c = it * 256 + t;
    const int row = c >> 4, c16 = c & 15;
    const size_t srcoff = (size_t)(row_base + row) * 256 + ((c16 * 16) ^ ((row & 7) << 4));
    gload_lds16((const char*)Xh + srcoff, XsB + c * 16);
  }
  __syncthreads();

  const int l = t & 63, w = t >> 6;
  const int r16 = l & 15, g16 = l >> 4;
  const int sw = (r16 & 7) << 4;
  f32x4 acc[8];
  #pragma unroll
  for (int n = 0; n < 8; ++n) acc[n] = (f32x4){0.f, 0.f, 0.f, 0.f};
  const char* ax = &XsB[(w * 16 + r16) * 256];
  #pragma unroll
  for (int kk = 0; kk < 4; ++kk) {
    const short8v a = *(const short8v*)(ax + ((kk * 64 + g16 * 16) ^ sw));
    #pragma unroll
    for (int n = 0; n < 8; ++n) {
      const short8v b = *(const short8v*)&WsB[((n * 4 + kk) * 64 + l) * 16];
      acc[n] = __builtin_amdgcn_mfma_f32_16x16x32_bf16(a, b, acc[n], 0, 0, 0);
    }
  }
  #pragma unroll
  for (int n = 0; n < 8; ++n) {
    const int col = n * 16 + r16;
    const float bvv = bo[col];
    #pragma unroll
    for (int r = 0; r < 4; ++r) {
      const int g = row_base + w * 16 + g16 * 4 + r;
      if (g < N) Y[(size_t)g * 128 + col] = acc[n][r] + bvv;
    }
  }
}

__global__ __launch_bounds__(256) void reduce_counts_kernel(
    const int* __restrict__ counts, int n, int* __restrict__ bsums)
{
  const int idx = blockIdx.x * 256 + threadIdx.x;
  int x = (idx < n) ? counts[idx] : 0;
  #pragma unroll
  for (int off = 1; off < 64; off <<= 1) x += __shfl_xor(x, off);
  __shared__ int ws[4];
  if ((threadIdx.x & 63) == 0) ws[threadIdx.x >> 6] = x;
  __syncthreads();
  if (threadIdx.x == 0) bsums[blockIdx.x] = ws[0] + ws[1] + ws[2] + ws[3];
}

__global__ __launch_bounds__(256) void scan_bsums_kernel(int* bsums, int nb)
{
  __shared__ int buf[256];
  const int t = threadIdx.x;
  const int x = (t < nb) ? bsums[t] : 0;
  buf[t] = x;
  __syncthreads();
  int val = x;
  #pragma unroll
  for (int off = 1; off < 256; off <<= 1) {
    const int other = (t >= off) ? buf[t - off] : 0;
    __syncthreads();
    val += other;
    buf[t] = val;
    __syncthreads();
  }
  if (t < nb) bsums[t] = val - x;
}

__global__ __launch_bounds__(256) void scan_counts_kernel(
    const int* __restrict__ counts, int n, const int* __restrict__ bsums,
    int* __restrict__ offsets)
{
  const int idx = blockIdx.x * 256 + threadIdx.x;
  const int lane = threadIdx.x & 63, wid = threadIdx.x >> 6;
  const int x = (idx < n) ? counts[idx] : 0;
  int v = x;
  #pragma unroll
  for (int off = 1; off < 64; off <<= 1) {
    const int t2 = __shfl_up(v, off);
    if (lane >= off) v += t2;
  }
  __shared__ int wsum[4];
  if (lane == 63) wsum[wid] = v;
  __syncthreads();
  int wbase = 0;
  for (int p = 0; p < wid; ++p) wbase += wsum[p];
  if (idx < n) offsets[idx] = bsums[blockIdx.x] + wbase + v - x;
}

__global__ __launch_bounds__(256) void scatter_kernel(
    const int* __restrict__ ei, int E, const int* __restrict__ offsets,
    int* __restrict__ cursor, int* __restrict__ csr_src)
{
  const int e = (blockIdx.x * 256 + threadIdx.x) * 4;
  if (e + 4 <= E) {
    const int4 s = *(const int4*)&ei[e];
    const int4 d = *(const int4*)&ei[E + e];
    int p;
    p = atomicAdd(&cursor[d.x], 1); csr_src[offsets[d.x] + p] = s.x;
    p = atomicAdd(&cursor[d.y], 1); csr_src[offsets[d.y] + p] = s.y;
    p = atomicAdd(&cursor[d.z], 1); csr_src[offsets[d.z] + p] = s.z;
    p = atomicAdd(&cursor[d.w], 1); csr_src[offsets[d.w] + p] = s.w;
  } else {
    for (int k = e; k < E; ++k) {
      const int d = ei[E + k];
      const int p = atomicAdd(&cursor[d], 1);
      csr_src[offsets[d] + p] = ei[k];
    }
  }
}

// One wave per destination; lane = (edge-slot eg=lane>>3, head h=lane&7).
// Each lane computes the FULL 16-dim dot for its (edge,head): no shfl in loop.
__global__ __launch_bounds__(256) void edge_attn_kernel(
    const unsigned short* __restrict__ qb, const unsigned short* __restrict__ kvb,
    const float* __restrict__ eb, const int* __restrict__ offsets,
    const int* __restrict__ counts, const int* __restrict__ csr_src,
    unsigned short* __restrict__ agg, int Ndst)
{
  const int wave = blockIdx.x * 4 + (threadIdx.x >> 6);
  if (wave >= Ndst) return;
  const int lane = threadIdx.x & 63;
  const int eg = lane >> 3, h = lane & 7;

  const uint4 q0 = *(const uint4*)&qb[(size_t)wave * 128 + h * 16];
  const uint4 q1 = *(const uint4*)&qb[(size_t)wave * 128 + h * 16 + 8];
  const float bias = eb[h];
  const int ro = offsets[wave];
  const int cnt = counts[wave];

  float acc[16];
  #pragma unroll
  for (int j = 0; j < 16; ++j) acc[j] = 0.f;
  float s = 0.f;

  for (int it = 0; it * 8 < cnt; ++it) {
    const int e = it * 8 + eg;
    const bool act = e < cnt;
    const int src = act ? csr_src[ro + e] : 0;
    const size_t base = (size_t)src * 256 + h * 16;
    const uint4 k0 = *(const uint4*)&kvb[base];
    const uint4 k1 = *(const uint4*)&kvb[base + 8];
    const uint4 v0 = *(const uint4*)&kvb[base + 128];
    const uint4 v1 = *(const uint4*)&kvb[base + 136];

    float p = 0.f;
    p = fmaf(bflo(q0.x), bflo(k0.x), p); p = fmaf(bfhi(q0.x), bfhi(k0.x), p);
    p = fmaf(bflo(q0.y), bflo(k0.y), p); p = fmaf(bfhi(q0.y), bfhi(k0.y), p);
    p = fmaf(bflo(q0.z), bflo(k0.z), p); p = fmaf(bfhi(q0.z), bfhi(k0.z), p);
    p = fmaf(bflo(q0.w), bflo(k0.w), p); p = fmaf(bfhi(q0.w), bfhi(k0.w), p);
    p = fmaf(bflo(q1.x), bflo(k1.x), p); p = fmaf(bfhi(q1.x), bfhi(k1.x), p);
    p = fmaf(bflo(q1.y), bflo(k1.y), p); p = fmaf(bfhi(q1.y), bfhi(k1.y), p);
    p = fmaf(bflo(q1.z), bflo(k1.z), p); p = fmaf(bfhi(q1.z), bfhi(k1.z), p);
    p = fmaf(bflo(q1.w), bflo(k1.w), p); p = fmaf(bfhi(q1.w), bfhi(k1.w), p);

    const float wgt = act ? __expf(fmaf(p, SCALE, bias)) : 0.f;
    s += wgt;
    acc[0]  = fmaf(wgt, bflo(v0.x), acc[0]);  acc[1]  = fmaf(wgt, bfhi(v0.x), acc[1]);
    acc[2]  = fmaf(wgt, bflo(v0.y), acc[2]);  acc[3]  = fmaf(wgt, bfhi(v0.y), acc[3]);
    acc[4]  = fmaf(wgt, bflo(v0.z), acc[4]);  acc[5]  = fmaf(wgt, bfhi(v0.z), acc[5]);
    acc[6]  = fmaf(wgt, bflo(v0.w), acc[6]);  acc[7]  = fmaf(wgt, bfhi(v0.w), acc[7]);
    acc[8]  = fmaf(wgt, bflo(v1.x), acc[8]);  acc[9]  = fmaf(wgt, bfhi(v1.x), acc[9]);
    acc[10] = fmaf(wgt, bflo(v1.y), acc[10]); acc[11] = fmaf(wgt, bfhi(v1.y), acc[11]);
    acc[12] = fmaf(wgt, bflo(v1.z), acc[12]); acc[13] = fmaf(wgt, bfhi(v1.z), acc[13]);
    acc[14] = fmaf(wgt, bflo(v1.w), acc[14]); acc[15] = fmaf(wgt, bfhi(v1.w), acc[15]);
  }

  #pragma unroll
  for (int m = 8; m <= 32; m <<= 1) {
    s += __shfl_xor(s, m);
    #pragma unroll
    for (int j = 0; j < 16; ++j) acc[j] += __shfl_xor(acc[j], m);
  }

  if (eg == 0) {
    const float rs = 1.0f / (s + 1e-8f);
    uint4 o0, o1;
    o0.x = (unsigned)f2bf(acc[0] * rs)  | ((unsigned)f2bf(acc[1] * rs) << 16);
    o0.y = (unsigned)f2bf(acc[2] * rs)  | ((unsigned)f2bf(acc[3] * rs) << 16);
    o0.z = (unsigned)f2bf(acc[4] * rs)  | ((unsigned)f2bf(acc[5] * rs) << 16);
    o0.w = (unsigned)f2bf(acc[6] * rs)  | ((unsigned)f2bf(acc[7] * rs) << 16);
    o1.x = (unsigned)f2bf(acc[8] * rs)  | ((unsigned)f2bf(acc[9] * rs) << 16);
    o1.y = (unsigned)f2bf(acc[10] * rs) | ((unsigned)f2bf(acc[11] * rs) << 16);
    o1.z = (unsigned)f2bf(acc[12] * rs) | ((unsigned)f2bf(acc[13] * rs) << 16);
    o1.w = (unsigned)f2bf(acc[14] * rs) | ((unsigned)f2bf(acc[15] * rs) << 16);
    *(uint4*)&agg[(size_t)wave * 128 + h * 16] = o0;
    *(uint4*)&agg[(size_t)wave * 128 + h * 16 + 8] = o1;
  }
}

extern "C" void kernel_launch(void* const* d_in, const int* in_sizes, int n_in,
                              void* d_out, int out_size, void* d_ws, size_t ws_size,
                              hipStream_t stream) {
  const float* x_src = (const float*)d_in[0];
  const float* x_dst = (const float*)d_in[1];
  const int*   ei    = (const int*)d_in[2];
  const float* Wq = (const float*)d_in[3];
  const float* bq = (const float*)d_in[4];
  const float* Wk = (const float*)d_in[5];
  const float* bk = (const float*)d_in[6];
  const float* Wv = (const float*)d_in[7];
  const float* bv = (const float*)d_in[8];
  const float* Wo = (const float*)d_in[9];
  const float* bo = (const float*)d_in[10];
  const float* eb = (const float*)d_in[11];

  const int Nsrc = in_sizes[0] / HIDDEN;
  const int Ndst = in_sizes[1] / HIDDEN;
  const int E    = in_sizes[2] / 2;

  char* w = (char*)d_ws;
  unsigned short* qb   = (unsigned short*)w; w += (size_t)Ndst * 128 * 2;
  unsigned short* kvb  = (unsigned short*)w; w += (size_t)Nsrc * 256 * 2;
  unsigned short* aggb = (unsigned short*)w; w += (size_t)Ndst * 128 * 2;
  unsigned short* Wb   = (unsigned short*)w; w += (size_t)4 * 16384 * 2;
  int* counts  = (int*)w; w += (size_t)Ndst * sizeof(int);
  int* cursor  = (int*)w; w += (size_t)Ndst * sizeof(int);
  int* offsets = (int*)w; w += (size_t)Ndst * sizeof(int);
  int* bsums   = (int*)w; w += 256 * sizeof(int);
  int* csr_src = (int*)w; w += (size_t)E * sizeof(int);

  hipMemsetAsync(counts, 0, (size_t)Ndst * 2 * sizeof(int), stream);  // counts+cursor

  dim3 blk256(256);
  const int e4blocks = (E / 4 + 255) / 256;
  prep_kernel<<<32 + e4blocks, blk256, 0, stream>>>(Wq, Wk, Wv, Wo, Wb, ei, E, counts);

  const int gb_dst = (Ndst + 63) / 64;
  const int gb_src = (Nsrc + 63) / 64;
  qkv_gemm_kernel<<<gb_src + gb_dst, blk256, 0, stream>>>(
      x_src, x_dst, Wb, bq, bk, bv, qb, kvb, Nsrc, Ndst, gb_src);

  const int nb = (Ndst + 255) / 256;
  reduce_counts_kernel<<<nb, blk256, 0, stream>>>(counts, Ndst, bsums);
  scan_bsums_kernel<<<1, blk256, 0, stream>>>(bsums, nb);
  scan_counts_kernel<<<nb, blk256, 0, stream>>>(counts, Ndst, bsums, offsets);

  scatter_kernel<<<e4blocks, blk256, 0, stream>>>(ei, E, offsets, cursor, csr_src);

  const int ablocks = (Ndst + 3) / 4;
  edge_attn_kernel<<<ablocks, blk256, 0, stream>>>(qb, kvb, eb, offsets, counts,
                                                   csr_src, aggb, Ndst);

  out_gemm_kernel<<<gb_dst, blk256, 0, stream>>>(aggb, Wb + 49152, bo, (float*)d_out, Ndst);
}

// Round 7
// 145.969 us; speedup vs baseline: 1.1847x; 1.0480x over previous
//
#include <hip/hip_runtime.h>
#include <math.h>

#define HIDDEN 128
#define SCALE 0.25f
#define NB_TYPE 170   // blocks per GEMM type (K,V,Q); grid = 510
#define NB_O 256

typedef __attribute__((ext_vector_type(8))) short short8v;
typedef __attribute__((ext_vector_type(4))) float f32x4;

__device__ __forceinline__ unsigned short f2bf(float f) {
  const unsigned u = __float_as_uint(f);
  const unsigned r = u + 0x7fffu + ((u >> 16) & 1u);   // RNE
  return (unsigned short)(r >> 16);
}
__device__ __forceinline__ unsigned pack_bf2(float a, float b) {
  unsigned r;
  asm("v_cvt_pk_bf16_f32 %0, %1, %2" : "=v"(r) : "v"(a), "v"(b));
  return r;
}
__device__ __forceinline__ float bflo(unsigned u) { return __uint_as_float(u << 16); }
__device__ __forceinline__ float bfhi(unsigned u) { return __uint_as_float(u & 0xffff0000u); }

__device__ __forceinline__ void gload_lds16(const void* g, void* l) {
  __builtin_amdgcn_global_load_lds(
      (const __attribute__((address_space(1))) unsigned*)g,
      (__attribute__((address_space(3))) unsigned*)l, 16, 0, 0);
}

// blocks 0..31: fragment-ordered bf16 weights: chunk m*2048+(n*4+kk)*64+l ->
//   W_m[n*16+(l&15)][kk*32+(l>>4)*8 + 0..7].  blocks 32..: count edges per dst.
__global__ __launch_bounds__(256) void prep_kernel(
    const float* __restrict__ W0, const float* __restrict__ W1,
    const float* __restrict__ W2, const float* __restrict__ W3,
    unsigned short* __restrict__ Wfrag,
    const int* __restrict__ ei, int E, int* __restrict__ counts)
{
  if (blockIdx.x < 32) {
    const int chunk = blockIdx.x * 256 + threadIdx.x;
    const int m = chunk >> 11;
    const int rem = chunk & 2047;
    const int l = rem & 63;
    const int nkk = rem >> 6;
    const int n = nkk >> 2, kk = nkk & 3;
    const float* W = (m == 0) ? W0 : (m == 1) ? W1 : (m == 2) ? W2 : W3;
    const int row = n * 16 + (l & 15);
    const int k0 = kk * 32 + (l >> 4) * 8;
    const float4 v0 = *(const float4*)&W[row * 128 + k0];
    const float4 v1 = *(const float4*)&W[row * 128 + k0 + 4];
    uint4 o;
    o.x = (unsigned)f2bf(v0.x) | ((unsigned)f2bf(v0.y) << 16);
    o.y = (unsigned)f2bf(v0.z) | ((unsigned)f2bf(v0.w) << 16);
    o.z = (unsigned)f2bf(v1.x) | ((unsigned)f2bf(v1.y) << 16);
    o.w = (unsigned)f2bf(v1.z) | ((unsigned)f2bf(v1.w) << 16);
    *(uint4*)&Wfrag[(size_t)chunk * 8] = o;
  } else {
    const int e = ((blockIdx.x - 32) * 256 + threadIdx.x) * 4;
    if (e + 4 <= E) {
      const int4 d = *(const int4*)&ei[E + e];
      atomicAdd(&counts[d.x], 1);
      atomicAdd(&counts[d.y], 1);
      atomicAdd(&counts[d.z], 1);
      atomicAdd(&counts[d.w], 1);
    } else {
      for (int k = e; k < E; ++k) atomicAdd(&counts[ei[E + k]], 1);
    }
  }
}

// Persistent, barrier-free QKV projection. Block type: K / V / Q by blockIdx.
// W-fragments live in 128 VGPRs (A-operand); swapped MFMA: acc = W x X^T ->
// lane (r16 = x-row-in-tile, g16) holds output cols n*16+g16*4+{0..3} for one row.
// All LDS regions wave-private (rows [16w,16w+16)): no __syncthreads anywhere.
__global__ __launch_bounds__(256, 2) void qkv_gemm_kernel(
    const float* __restrict__ x_src, const float* __restrict__ x_dst,
    const unsigned short* __restrict__ Wfrag,
    const float* __restrict__ bq, const float* __restrict__ bk,
    const float* __restrict__ bv,
    unsigned short* __restrict__ qb, unsigned short* __restrict__ kvb,
    int Nsrc, int Ndst)
{
  __shared__ __align__(16) char Xs[2][16384];   // 64 rows x 128 bf16, swizzled
  const int t = threadIdx.x;
  const int l = t & 63, w = t >> 6;
  const int r16 = l & 15, g16 = l >> 4;

  int bid = blockIdx.x;
  const float* X; const float* bias; const unsigned short* wbase;
  unsigned short* out; int ostride, ooff, N;
  if (bid < NB_TYPE)          { X = x_src; bias = bk; wbase = Wfrag + 16384; out = kvb; ostride = 256; ooff = 0;   N = Nsrc; }
  else if (bid < 2 * NB_TYPE) { bid -= NB_TYPE;   X = x_src; bias = bv; wbase = Wfrag + 32768; out = kvb; ostride = 256; ooff = 128; N = Nsrc; }
  else                        { bid -= 2 * NB_TYPE; X = x_dst; bias = bq; wbase = Wfrag;       out = qb;  ostride = 128; ooff = 0;   N = Ndst; }
  const int ntiles = (N + 63) >> 6;

  short8v wfr[32];                       // full W, fragment order, in registers
  #pragma unroll
  for (int i = 0; i < 32; ++i) wfr[i] = ((const short8v*)wbase)[i * 64 + l];

  const int srow = l >> 5;               // staging: 2 rows per wave per iter
  const int scol = (l & 31) * 4;

  float4 xv[8];
  int tile = bid;
  {  // prologue: stage tile0 into buf0
    #pragma unroll
    for (int j = 0; j < 8; ++j) {
      const int r = j * 2 + srow;
      const int g = tile * 64 + w * 16 + r;
      xv[j] = make_float4(0.f, 0.f, 0.f, 0.f);
      if (g < N) xv[j] = *(const float4*)&X[(size_t)g * 128 + scol];
    }
    #pragma unroll
    for (int j = 0; j < 8; ++j) {
      const int r = j * 2 + srow;
      uint2 p;
      p.x = pack_bf2(xv[j].x, xv[j].y);
      p.y = pack_bf2(xv[j].z, xv[j].w);
      *(uint2*)&Xs[0][(w * 16 + r) * 256 + ((scol * 2) ^ ((r & 7) << 4))] = p;
    }
  }
  int cur = 0;
  for (; tile < ntiles; tile += NB_TYPE) {
    const int nt = tile + NB_TYPE;
    if (nt < ntiles) {                   // issue prefetch loads early (T14)
      #pragma unroll
      for (int j = 0; j < 8; ++j) {
        const int r = j * 2 + srow;
        const int g = nt * 64 + w * 16 + r;
        xv[j] = make_float4(0.f, 0.f, 0.f, 0.f);
        if (g < N) xv[j] = *(const float4*)&X[(size_t)g * 128 + scol];
      }
    }
    f32x4 acc[8];
    #pragma unroll
    for (int n = 0; n < 8; ++n) {        // C-in = bias (per output col)
      const float4 bb = *(const float4*)&bias[n * 16 + g16 * 4];
      acc[n] = (f32x4){bb.x, bb.y, bb.z, bb.w};
    }
    const char* ax = &Xs[cur][(w * 16 + r16) * 256];
    #pragma unroll
    for (int kk = 0; kk < 4; ++kk) {
      const short8v b = *(const short8v*)(ax + ((kk * 64 + g16 * 16) ^ ((r16 & 7) << 4)));
      #pragma unroll
      for (int n = 0; n < 8; ++n)
        acc[n] = __builtin_amdgcn_mfma_f32_16x16x32_bf16(wfr[n * 4 + kk], b, acc[n], 0, 0, 0);
    }
    const int grow = tile * 64 + w * 16 + r16;
    if (grow < N) {
      unsigned short* orow = out + (size_t)grow * ostride + ooff;
      #pragma unroll
      for (int n = 0; n < 8; ++n) {
        uint2 o;
        o.x = pack_bf2(acc[n][0], acc[n][1]);
        o.y = pack_bf2(acc[n][2], acc[n][3]);
        *(uint2*)&orow[n * 16 + g16 * 4] = o;
      }
    }
    if (nt < ntiles) {                   // write prefetched tile into other buf
      #pragma unroll
      for (int j = 0; j < 8; ++j) {
        const int r = j * 2 + srow;
        uint2 p;
        p.x = pack_bf2(xv[j].x, xv[j].y);
        p.y = pack_bf2(xv[j].z, xv[j].w);
        *(uint2*)&Xs[cur ^ 1][(w * 16 + r) * 256 + ((scol * 2) ^ ((r & 7) << 4))] = p;
      }
    }
    cur ^= 1;
  }
}

// Output projection, same structure; bf16 input staged via global_load_lds with
// pre-swizzled per-lane SOURCE (linear wave-private LDS dest), f32 float4 epilogue.
__global__ __launch_bounds__(256, 2) void out_gemm_kernel(
    const unsigned short* __restrict__ agg, const unsigned short* __restrict__ Wo_frag,
    const float* __restrict__ bo, float* __restrict__ Y, int N)
{
  __shared__ __align__(16) char Xs[2][16384];
  const int t = threadIdx.x;
  const int l = t & 63, w = t >> 6;
  const int r16 = l & 15, g16 = l >> 4;
  const int ntiles = (N + 63) >> 6;

  short8v wfr[32];
  #pragma unroll
  for (int i = 0; i < 32; ++i) wfr[i] = ((const short8v*)Wo_frag)[i * 64 + l];

  int tile = blockIdx.x;
  {  // prologue issue
    #pragma unroll
    for (int it = 0; it < 4; ++it) {
      const int row16 = it * 4 + (l >> 4);
      const int grow = tile * 64 + w * 16 + row16;
      const int sb = ((l & 15) * 16) ^ ((row16 & 7) << 4);
      gload_lds16((const char*)agg + (size_t)grow * 256 + sb,
                  &Xs[0][w * 4096 + it * 1024 + l * 16]);
    }
  }
  int cur = 0;
  for (; tile < ntiles; tile += NB_O) {
    const int nt = tile + NB_O;
    asm volatile("s_waitcnt vmcnt(0)" ::: "memory");
    __builtin_amdgcn_sched_barrier(0);
    if (nt < ntiles) {
      #pragma unroll
      for (int it = 0; it < 4; ++it) {
        const int row16 = it * 4 + (l >> 4);
        const int grow = nt * 64 + w * 16 + row16;
        const int sb = ((l & 15) * 16) ^ ((row16 & 7) << 4);
        gload_lds16((const char*)agg + (size_t)grow * 256 + sb,
                    &Xs[cur ^ 1][w * 4096 + it * 1024 + l * 16]);
      }
    }
    f32x4 acc[8];
    #pragma unroll
    for (int n = 0; n < 8; ++n) {
      const float4 bb = *(const float4*)&bo[n * 16 + g16 * 4];
      acc[n] = (f32x4){bb.x, bb.y, bb.z, bb.w};
    }
    const char* ax = &Xs[cur][(w * 16 + r16) * 256];
    #pragma unroll
    for (int kk = 0; kk < 4; ++kk) {
      const short8v b = *(const short8v*)(ax + ((kk * 64 + g16 * 16) ^ ((r16 & 7) << 4)));
      #pragma unroll
      for (int n = 0; n < 8; ++n)
        acc[n] = __builtin_amdgcn_mfma_f32_16x16x32_bf16(wfr[n * 4 + kk], b, acc[n], 0, 0, 0);
    }
    const int grow = tile * 64 + w * 16 + r16;
    if (grow < N) {
      float* yrow = Y + (size_t)grow * 128;
      #pragma unroll
      for (int n = 0; n < 8; ++n)
        *(float4*)&yrow[n * 16 + g16 * 4] = make_float4(acc[n][0], acc[n][1], acc[n][2], acc[n][3]);
    }
    cur ^= 1;
  }
}

__global__ __launch_bounds__(256) void reduce_counts_kernel(
    const int* __restrict__ counts, int n, int* __restrict__ bsums)
{
  const int idx = blockIdx.x * 256 + threadIdx.x;
  int x = (idx < n) ? counts[idx] : 0;
  #pragma unroll
  for (int off = 1; off < 64; off <<= 1) x += __shfl_xor(x, off);
  __shared__ int ws[4];
  if ((threadIdx.x & 63) == 0) ws[threadIdx.x >> 6] = x;
  __syncthreads();
  if (threadIdx.x == 0) bsums[blockIdx.x] = ws[0] + ws[1] + ws[2] + ws[3];
}

__global__ __launch_bounds__(256) void scan_bsums_kernel(int* bsums, int nb)
{
  __shared__ int buf[256];
  const int t = threadIdx.x;
  const int x = (t < nb) ? bsums[t] : 0;
  buf[t] = x;
  __syncthreads();
  int val = x;
  #pragma unroll
  for (int off = 1; off < 256; off <<= 1) {
    const int other = (t >= off) ? buf[t - off] : 0;
    __syncthreads();
    val += other;
    buf[t] = val;
    __syncthreads();
  }
  if (t < nb) bsums[t] = val - x;
}

__global__ __launch_bounds__(256) void scan_counts_kernel(
    const int* __restrict__ counts, int n, const int* __restrict__ bsums,
    int* __restrict__ offsets)
{
  const int idx = blockIdx.x * 256 + threadIdx.x;
  const int lane = threadIdx.x & 63, wid = threadIdx.x >> 6;
  const int x = (idx < n) ? counts[idx] : 0;
  int v = x;
  #pragma unroll
  for (int off = 1; off < 64; off <<= 1) {
    const int t2 = __shfl_up(v, off);
    if (lane >= off) v += t2;
  }
  __shared__ int wsum[4];
  if (lane == 63) wsum[wid] = v;
  __syncthreads();
  int wbase = 0;
  for (int p = 0; p < wid; ++p) wbase += wsum[p];
  if (idx < n) offsets[idx] = bsums[blockIdx.x] + wbase + v - x;
}

__global__ __launch_bounds__(256) void scatter_kernel(
    const int* __restrict__ ei, int E, const int* __restrict__ offsets,
    int* __restrict__ cursor, int* __restrict__ csr_src)
{
  const int e = (blockIdx.x * 256 + threadIdx.x) * 4;
  if (e + 4 <= E) {
    const int4 s = *(const int4*)&ei[e];
    const int4 d = *(const int4*)&ei[E + e];
    int p;
    p = atomicAdd(&cursor[d.x], 1); csr_src[offsets[d.x] + p] = s.x;
    p = atomicAdd(&cursor[d.y], 1); csr_src[offsets[d.y] + p] = s.y;
    p = atomicAdd(&cursor[d.z], 1); csr_src[offsets[d.z] + p] = s.z;
    p = atomicAdd(&cursor[d.w], 1); csr_src[offsets[d.w] + p] = s.w;
  } else {
    for (int k = e; k < E; ++k) {
      const int d = ei[E + k];
      const int p = atomicAdd(&cursor[d], 1);
      csr_src[offsets[d] + p] = ei[k];
    }
  }
}

// One wave per destination; lane = (edge-slot eg=lane>>3, head h=lane&7).
__global__ __launch_bounds__(256) void edge_attn_kernel(
    const unsigned short* __restrict__ qb, const unsigned short* __restrict__ kvb,
    const float* __restrict__ eb, const int* __restrict__ offsets,
    const int* __restrict__ counts, const int* __restrict__ csr_src,
    unsigned short* __restrict__ agg, int Ndst)
{
  const int wave = blockIdx.x * 4 + (threadIdx.x >> 6);
  if (wave >= Ndst) return;
  const int lane = threadIdx.x & 63;
  const int eg = lane >> 3, h = lane & 7;

  const uint4 q0 = *(const uint4*)&qb[(size_t)wave * 128 + h * 16];
  const uint4 q1 = *(const uint4*)&qb[(size_t)wave * 128 + h * 16 + 8];
  const float bias = eb[h];
  const int ro = offsets[wave];
  const int cnt = counts[wave];

  float acc[16];
  #pragma unroll
  for (int j = 0; j < 16; ++j) acc[j] = 0.f;
  float s = 0.f;

  for (int it = 0; it * 8 < cnt; ++it) {
    const int e = it * 8 + eg;
    const bool act = e < cnt;
    const int src = act ? csr_src[ro + e] : 0;
    const size_t base = (size_t)src * 256 + h * 16;
    const uint4 k0 = *(const uint4*)&kvb[base];
    const uint4 k1 = *(const uint4*)&kvb[base + 8];
    const uint4 v0 = *(const uint4*)&kvb[base + 128];
    const uint4 v1 = *(const uint4*)&kvb[base + 136];

    float p = 0.f;
    p = fmaf(bflo(q0.x), bflo(k0.x), p); p = fmaf(bfhi(q0.x), bfhi(k0.x), p);
    p = fmaf(bflo(q0.y), bflo(k0.y), p); p = fmaf(bfhi(q0.y), bfhi(k0.y), p);
    p = fmaf(bflo(q0.z), bflo(k0.z), p); p = fmaf(bfhi(q0.z), bfhi(k0.z), p);
    p = fmaf(bflo(q0.w), bflo(k0.w), p); p = fmaf(bfhi(q0.w), bfhi(k0.w), p);
    p = fmaf(bflo(q1.x), bflo(k1.x), p); p = fmaf(bfhi(q1.x), bfhi(k1.x), p);
    p = fmaf(bflo(q1.y), bflo(k1.y), p); p = fmaf(bfhi(q1.y), bfhi(k1.y), p);
    p = fmaf(bflo(q1.z), bflo(k1.z), p); p = fmaf(bfhi(q1.z), bfhi(k1.z), p);
    p = fmaf(bflo(q1.w), bflo(k1.w), p); p = fmaf(bfhi(q1.w), bfhi(k1.w), p);

    const float wgt = act ? __expf(fmaf(p, SCALE, bias)) : 0.f;
    s += wgt;
    acc[0]  = fmaf(wgt, bflo(v0.x), acc[0]);  acc[1]  = fmaf(wgt, bfhi(v0.x), acc[1]);
    acc[2]  = fmaf(wgt, bflo(v0.y), acc[2]);  acc[3]  = fmaf(wgt, bfhi(v0.y), acc[3]);
    acc[4]  = fmaf(wgt, bflo(v0.z), acc[4]);  acc[5]  = fmaf(wgt, bfhi(v0.z), acc[5]);
    acc[6]  = fmaf(wgt, bflo(v0.w), acc[6]);  acc[7]  = fmaf(wgt, bfhi(v0.w), acc[7]);
    acc[8]  = fmaf(wgt, bflo(v1.x), acc[8]);  acc[9]  = fmaf(wgt, bfhi(v1.x), acc[9]);
    acc[10] = fmaf(wgt, bflo(v1.y), acc[10]); acc[11] = fmaf(wgt, bfhi(v1.y), acc[11]);
    acc[12] = fmaf(wgt, bflo(v1.z), acc[12]); acc[13] = fmaf(wgt, bfhi(v1.z), acc[13]);
    acc[14] = fmaf(wgt, bflo(v1.w), acc[14]); acc[15] = fmaf(wgt, bfhi(v1.w), acc[15]);
  }

  #pragma unroll
  for (int m = 8; m <= 32; m <<= 1) {
    s += __shfl_xor(s, m);
    #pragma unroll
    for (int j = 0; j < 16; ++j) acc[j] += __shfl_xor(acc[j], m);
  }

  if (eg == 0) {
    const float rs = 1.0f / (s + 1e-8f);
    uint4 o0, o1;
    o0.x = pack_bf2(acc[0] * rs,  acc[1] * rs);
    o0.y = pack_bf2(acc[2] * rs,  acc[3] * rs);
    o0.z = pack_bf2(acc[4] * rs,  acc[5] * rs);
    o0.w = pack_bf2(acc[6] * rs,  acc[7] * rs);
    o1.x = pack_bf2(acc[8] * rs,  acc[9] * rs);
    o1.y = pack_bf2(acc[10] * rs, acc[11] * rs);
    o1.z = pack_bf2(acc[12] * rs, acc[13] * rs);
    o1.w = pack_bf2(acc[14] * rs, acc[15] * rs);
    *(uint4*)&agg[(size_t)wave * 128 + h * 16] = o0;
    *(uint4*)&agg[(size_t)wave * 128 + h * 16 + 8] = o1;
  }
}

extern "C" void kernel_launch(void* const* d_in, const int* in_sizes, int n_in,
                              void* d_out, int out_size, void* d_ws, size_t ws_size,
                              hipStream_t stream) {
  const float* x_src = (const float*)d_in[0];
  const float* x_dst = (const float*)d_in[1];
  const int*   ei    = (const int*)d_in[2];
  const float* Wq = (const float*)d_in[3];
  const float* bq = (const float*)d_in[4];
  const float* Wk = (const float*)d_in[5];
  const float* bk = (const float*)d_in[6];
  const float* Wv = (const float*)d_in[7];
  const float* bv = (const float*)d_in[8];
  const float* Wo = (const float*)d_in[9];
  const float* bo = (const float*)d_in[10];
  const float* eb = (const float*)d_in[11];

  const int Nsrc = in_sizes[0] / HIDDEN;
  const int Ndst = in_sizes[1] / HIDDEN;
  const int E    = in_sizes[2] / 2;

  char* w = (char*)d_ws;
  unsigned short* qb   = (unsigned short*)w; w += (size_t)Ndst * 128 * 2;
  unsigned short* kvb  = (unsigned short*)w; w += (size_t)Nsrc * 256 * 2;
  unsigned short* aggb = (unsigned short*)w; w += (size_t)Ndst * 128 * 2;
  unsigned short* Wb   = (unsigned short*)w; w += (size_t)4 * 16384 * 2;
  int* counts  = (int*)w; w += (size_t)Ndst * sizeof(int);
  int* cursor  = (int*)w; w += (size_t)Ndst * sizeof(int);
  int* offsets = (int*)w; w += (size_t)Ndst * sizeof(int);
  int* bsums   = (int*)w; w += 256 * sizeof(int);
  int* csr_src = (int*)w; w += (size_t)E * sizeof(int);

  hipMemsetAsync(counts, 0, (size_t)Ndst * 2 * sizeof(int), stream);  // counts+cursor

  dim3 blk256(256);
  const int e4blocks = (E / 4 + 255) / 256;
  prep_kernel<<<32 + e4blocks, blk256, 0, stream>>>(Wq, Wk, Wv, Wo, Wb, ei, E, counts);

  qkv_gemm_kernel<<<3 * NB_TYPE, blk256, 0, stream>>>(
      x_src, x_dst, Wb, bq, bk, bv, qb, kvb, Nsrc, Ndst);

  const int nb = (Ndst + 255) / 256;
  reduce_counts_kernel<<<nb, blk256, 0, stream>>>(counts, Ndst, bsums);
  scan_bsums_kernel<<<1, blk256, 0, stream>>>(bsums, nb);
  scan_counts_kernel<<<nb, blk256, 0, stream>>>(counts, Ndst, bsums, offsets);

  scatter_kernel<<<e4blocks, blk256, 0, stream>>>(ei, E, offsets, cursor, csr_src);

  const int ablocks = (Ndst + 3) / 4;
  edge_attn_kernel<<<ablocks, blk256, 0, stream>>>(qb, kvb, eb, offsets, counts,
                                                   csr_src, aggb, Ndst);

  out_gemm_kernel<<<NB_O, blk256, 0, stream>>>(aggb, Wb + 49152, bo, (float*)d_out, Ndst);
}